// Round 2
// baseline (122.666 us; speedup 1.0000x reference)
//
#include <hip/hip_runtime.h>
#include <math.h>
#include <float.h>

// b=8, c=64, H=W=64, KS=8 -> P = 57*57 = 3249.
// Stage 1 per (b,c): G[m,n] = <patch_m, patch_n> over P; corr = G/(sqrt(diag)sqrt(diag)P);
//   sort 64 m per column n desc; ranks {1,9,16,24,32,40,48,55,63} -> xp[b,c,576].
// Stage 2 per b: corr2[p,q] = sum_c Xn[c,p]Xn[c,q]/64; sort 576 p per q desc; 115 ranks.
//
// R8: k3 9-reg reg-major 576 merge-tree (zero padding).
// R9: ALL cross-lane sort traffic moved off the LDS pipe onto VALU:
//     xor-1/2 = quad_perm DPP; xor-4 = bank-masked row_shl:4/row_shr:4 DPP pair;
//     xor-8 = row_ror:8 DPP; xor-16/32 = v_permlane16/32_swap + cndmask.
//     k1's shfl_up(P,57) replaced by row0-broadcast (2 permlane swaps) + row_shr:9.

#define IMGS 65

typedef unsigned int uint2v __attribute__((ext_vector_type(2)));

#if __has_builtin(__builtin_amdgcn_permlane16_swap) && __has_builtin(__builtin_amdgcn_permlane32_swap)
#define HAS_PLSWAP 1
#else
#define HAS_PLSWAP 0
#endif

// ---- DPP helpers (compile-time ctrl via templates; LDS-pipe-free cross-lane) ----
template<int CTRL, int RM>
__device__ __forceinline__ float dpp_add(float x) {
    int o = __builtin_amdgcn_update_dpp(0, __float_as_int(x), CTRL, RM, 0xf, true);
    return x + __int_as_float(o);
}
template<int CTRL>
__device__ __forceinline__ float dpp_perm(float x) {
    int o = __builtin_amdgcn_update_dpp(__float_as_int(x), __float_as_int(x), CTRL, 0xf, 0xf, false);
    return __int_as_float(o);
}
// xor-1 / xor-2 within quads
#define QP_XOR1 0xB1   // [1,0,3,2]
#define QP_XOR2 0x4E   // [2,3,0,1]

// ---- xor-J lane exchange, all on the VALU pipe (no ds_swizzle / ds_bpermute) ----
template<int J>
__device__ __forceinline__ float shx(float x) {
    const int lane = threadIdx.x & 63;
    if constexpr (J == 1)       return dpp_perm<QP_XOR1>(x);
    else if constexpr (J == 2)  return dpp_perm<QP_XOR2>(x);
    else if constexpr (J == 4) {
        // banks 0,2 ((pos&4)==0) take row_shl:4 (src lane+4); banks 1,3 take row_shr:4
        int t0 = __builtin_amdgcn_update_dpp(0,  __float_as_int(x), 0x104, 0xf, 0x5, false);
        int t1 = __builtin_amdgcn_update_dpp(t0, __float_as_int(x), 0x114, 0xf, 0xA, false);
        return __int_as_float(t1);
    }
    else if constexpr (J == 8) {
        int t = __builtin_amdgcn_update_dpp(0, __float_as_int(x), 0x128, 0xf, 0xf, false); // row_ror:8
        return __int_as_float(t);
    }
#if HAS_PLSWAP
    else if constexpr (J == 16) {
        // pr.x = [r0,r0,r2,r2], pr.y = [r1,r1,r3,r3]  (position-preserving row swap)
        uint2v pr = __builtin_amdgcn_permlane16_swap((unsigned)__float_as_int(x),
                                                     (unsigned)__float_as_int(x), false, false);
        return __int_as_float((int)((lane & 16) ? pr.x : pr.y));
    }
    else {
        // pr.x = [lo,lo], pr.y = [hi,hi]
        uint2v pr = __builtin_amdgcn_permlane32_swap((unsigned)__float_as_int(x),
                                                     (unsigned)__float_as_int(x), false, false);
        return __int_as_float((int)((lane & 32) ? pr.x : pr.y));
    }
#else
    else if constexpr (J == 16)
        return __int_as_float(__builtin_amdgcn_ds_swizzle(__float_as_int(x), (16 << 10) | 0x1F));
    else
        return __shfl_xor(x, 32, 64);
#endif
}

template<int J>
__device__ __forceinline__ void cex(float& v, const bool keep_max) {
    const float o = shx<J>(v);
    v = keep_max ? fmaxf(v, o) : fminf(v, o);
}

// in-lane compare-exchange between two regs; DESC: a (lower position) keeps max
template<int DESC>
__device__ __forceinline__ void cer(float& a, float& b) {
    const float mx = fmaxf(a, b), mn = fminf(a, b);
    if constexpr (DESC) { a = mx; b = mn; } else { a = mn; b = mx; }
}

// bitonic merge of a 64-element bitonic sequence held across lanes in one reg
template<int DESC>
__device__ __forceinline__ void merge64(float& v, const int lane) {
    cex<32>(v, (((lane & 32) != 0) ^ DESC) != 0);
    cex<16>(v, (((lane & 16) != 0) ^ DESC) != 0);
    cex<8>(v,  (((lane &  8) != 0) ^ DESC) != 0);
    cex<4>(v,  (((lane &  4) != 0) ^ DESC) != 0);
    cex<2>(v,  (((lane &  2) != 0) ^ DESC) != 0);
    cex<1>(v,  (((lane &  1) != 0) ^ DESC) != 0);
}

// ---- width-57 window sum via row scans; subtrahend fetched with permlane row0-bcast ----
// returns S[lane] = P_incl[lane] - P_incl[lane-57]  (P_incl[<0] := 0); valid on lanes >= 56
__device__ __forceinline__ float scan_win57(float x) {
    x = dpp_add<0x111, 0xf>(x);
    x = dpp_add<0x112, 0xf>(x);
    x = dpp_add<0x114, 0xf>(x);
    x = dpp_add<0x118, 0xf>(x);
    const float rs = x;                         // inclusive scan within 16-lane rows
    float P = dpp_add<0x142, 0xa>(rs);          // += row0[15] / row2[15] into rows 1,3
    P = dpp_add<0x143, 0xc>(P);                 // += scan[31] into rows 2,3
#if HAS_PLSWAP
    uint2v a  = __builtin_amdgcn_permlane16_swap((unsigned)__float_as_int(rs),
                                                 (unsigned)__float_as_int(rs), false, false);
    uint2v b2 = __builtin_amdgcn_permlane32_swap(a.x, a.x, false, false);   // row0 -> all rows
    int c = __builtin_amdgcn_update_dpp(0, (int)b2.x, 0x119, 0xf, 0xf, true); // row_shr:9, 0-fill
    return P - __int_as_float(c);               // lane 56+ki: P - rs_row0[ki-1] (ki=0 -> -0)
#else
    float sl = __shfl_up(P, 57, 64);
    return P - (((threadIdx.x & 63) >= 57) ? sl : 0.0f);
#endif
}

__host__ __device__ constexpr int offF(int dj) { return dj * (17 - dj) / 2; }       // 36 total
__host__ __device__ constexpr int offB(int dj) { return (dj - 1) * (16 - dj) / 2; } // 28 total

// ---------------- k1: fused stage-1, pair-symmetric, canonical-G ----------------
// grid = 512 (bc), block = 512 (8 waves; wave wv handles row-shift d = wv)
__global__ __launch_bounds__(512) void k1(const float* __restrict__ x,
                                          float* __restrict__ xp) {
    __shared__ float img[64 * IMGS];   // 16.6 KB
    __shared__ float G[64 * IMGS];     // canonical: G[m*65+n], m<=n

    const int t = threadIdx.x;
    const int bc = blockIdx.x;
    const float* src = x + (size_t)bc * 4096;

    #pragma unroll
    for (int k = 0; k < 2; ++k) {
        int i4 = t + k * 512;
        float4 v = ((const float4*)src)[i4];
        int fl = i4 * 4, row = fl >> 6, col = fl & 63;
        float* dd = &img[row * IMGS + col];
        dd[0] = v.x; dd[1] = v.y; dd[2] = v.z; dd[3] = v.w;
    }
    __syncthreads();

    const int wv = t >> 6, lane = t & 63;
    const int d = wv;                            // 0..7
    const int a = lane;
    const bool av = (a + d <= 63);
    const int a1 = min(a + d, 63);
    const float* r0 = &img[a * IMGS];
    const float* r1 = &img[a1 * IMGS];

    // ---- FMA phase: wf[k]=sum r0[u]*r1[u+k], wb[k]=sum r1[u]*r0[u+k]  (u=0..56) ----
    float wf[8] = {0,0,0,0,0,0,0,0}, wb[8] = {0,0,0,0,0,0,0,0};
    float sf[8], sb[8], hf[7], hb[7];
    #pragma unroll
    for (int k = 0; k < 7; ++k) { sf[k] = r1[k]; sb[k] = r0[k]; hf[k] = sf[k]; hb[k] = sb[k]; }
    #pragma unroll
    for (int c = 0; c < 7; ++c) {
        #pragma unroll
        for (int j = 0; j < 8; ++j) {
            const int u = c * 8 + j;
            sf[(j + 7) & 7] = r1[u + 7];
            sb[(j + 7) & 7] = r0[u + 7];
            const float f0 = sb[j & 7];          // r0[u]
            const float g0 = sf[j & 7];          // r1[u]
            #pragma unroll
            for (int k = 0; k < 8; ++k) wf[k] = fmaf(f0, sf[(j + k) & 7], wf[k]);
            #pragma unroll
            for (int k = 1; k < 8; ++k) wb[k] = fmaf(g0, sb[(j + k) & 7], wb[k]);
        }
    }
    {   // u = 56 (j-pattern 0)
        sf[7] = r1[63]; sb[7] = r0[63];
        const float f0 = sb[0], g0 = sf[0];
        #pragma unroll
        for (int k = 0; k < 8; ++k) wf[k] = fmaf(f0, sf[k], wf[k]);
        #pragma unroll
        for (int k = 1; k < 8; ++k) wb[k] = fmaf(g0, sb[k], wb[k]);
    }
    // now sf[k] = r1[56+k], sb[k] = r0[56+k]  (tails); hf/hb = heads

    // ---- slide over st (all indices compile-time) ----
    float Wf[36], Wb[28];
    #pragma unroll
    for (int dj = 0; dj < 8; ++dj) {
        float a0 = wf[dj];
        Wf[offF(dj)] = a0;
        #pragma unroll
        for (int st = 1; st < 8 - dj; ++st) {
            a0 += sb[st] * sf[st + dj] - hb[st - 1] * hf[st - 1 + dj];
            Wf[offF(dj) + st] = a0;
        }
    }
    #pragma unroll
    for (int dj = 1; dj < 8; ++dj) {
        float a0 = wb[dj];
        Wb[offB(dj)] = a0;
        #pragma unroll
        for (int st = 1; st < 8 - dj; ++st) {
            a0 += sf[st] * sb[st + dj] - hf[st - 1] * hb[st - 1 + dj];
            Wb[offB(dj) + st] = a0;
        }
    }

    // ---- mask invalid rows; windowed scan (VALU-only, subtrahend via permlane bcast) ----
    const float msk = av ? 1.0f : 0.0f;
    #pragma unroll
    for (int i = 0; i < 36; ++i) Wf[i] = scan_win57(Wf[i] * msk);
    if (d > 0) {
        #pragma unroll
        for (int i = 0; i < 28; ++i) Wb[i] = scan_win57(Wb[i] * msk);
    }

    // ---- write canonical G from lanes 56..63-d (S already materialized per lane) ----
    const bool wr = (lane >= 56) && (lane <= 63 - d);
    const int ki = lane - 56;
    #pragma unroll
    for (int dj = 0; dj < 8; ++dj) {
        #pragma unroll
        for (int st = 0; st < 8 - dj; ++st) {
            if (wr) G[(ki * 8 + st) * IMGS + ((ki + d) * 8 + st + dj)] = Wf[offF(dj) + st];
            if (d > 0 && dj > 0) {
                if (wr) G[(ki * 8 + st + dj) * IMGS + ((ki + d) * 8 + st)] = Wb[offB(dj) + st];
            }
        }
    }
    __syncthreads();

    // ---- normalize + batched sort64 (wave wv: columns wv*8..wv*8+7) ----
    const int m = lane;
    const float invm = 1.0f / fmaxf(sqrtf(G[m * 66]), 1e-12f);
    const float sc = 1.0f / 3249.0f;
    const int c0 = wv * 8;
    float v[8];
    #pragma unroll
    for (int cc = 0; cc < 8; ++cc) {
        const int col = c0 + cc;
        const int addr = (m <= col) ? m * IMGS + col : col * IMGS + m;   // symmetric read
        const float invc = __shfl(invm, col, 64);
        v[cc] = G[addr] * invm * invc * sc;
    }
    // bitonic sort64, descending; keep_max = ((lane&KK)==0) ^ ((lane&J)!=0)
    #define K1S(KK, J) { \
        const bool km = (((lane & (KK)) == 0) != ((lane & (J)) != 0)); \
        _Pragma("unroll") \
        for (int cc = 0; cc < 8; ++cc) cex<J>(v[cc], km); }
    K1S(2, 1)
    K1S(4, 2)   K1S(4, 1)
    K1S(8, 4)   K1S(8, 2)   K1S(8, 1)
    K1S(16, 8)  K1S(16, 4)  K1S(16, 2)  K1S(16, 1)
    K1S(32, 16) K1S(32, 8)  K1S(32, 4)  K1S(32, 2)  K1S(32, 1)
    K1S(64, 32) K1S(64, 16) K1S(64, 8)  K1S(64, 4)  K1S(64, 2) K1S(64, 1)
    #undef K1S
    // ranks2 = {1,9,16,24,32,40,48,55,63}
    int ridx = -1;
    if      (lane ==  1) ridx = 0; else if (lane ==  9) ridx = 1; else if (lane == 16) ridx = 2;
    else if (lane == 24) ridx = 3; else if (lane == 32) ridx = 4; else if (lane == 40) ridx = 5;
    else if (lane == 48) ridx = 6; else if (lane == 55) ridx = 7; else if (lane == 63) ridx = 8;
    if (ridx >= 0) {
        float* dst = xp + (size_t)bc * 576 + ridx * 64 + c0;
        *(float4*)&dst[0] = make_float4(v[0], v[1], v[2], v[3]);
        *(float4*)&dst[4] = make_float4(v[4], v[5], v[6], v[7]);
    }
}

// ---------------- k3: fused stage-2 (Gram columns + norms + sort + ranks) ----------------
// grid = 8*64 (b x q-group of 9), block = 576 (9 waves; wave sorts column q0+wv)
__global__ __launch_bounds__(576) void k3(const float* __restrict__ xp,
                                          float* __restrict__ out) {
    __shared__ __align__(16) float sbuf[9 * 580];   // raw corr columns, stride 580
    __shared__ __align__(16) float ipL[576];        // per-p inverse channel norms
    __shared__ float rankbuf[115 * 12];
    const int t = threadIdx.x;
    const int b = blockIdx.x >> 6, qg = blockIdx.x & 63;
    const int q0 = qg * 9;
    const float* __restrict__ xb = xp + (size_t)b * 36864;

    // ---- phase 1: thread p computes raw corr2 col entries for 9 q's + own norm ----
    {
        const int p = t;
        float acc[9] = {0,0,0,0,0,0,0,0,0};
        float sd = 0.f;
        #pragma unroll 8
        for (int c = 0; c < 64; ++c) {
            const float xv = xb[c * 576 + p];                  // coalesced vector load
            sd = fmaf(xv, xv, sd);
            #pragma unroll
            for (int qq = 0; qq < 9; ++qq)
                acc[qq] = fmaf(xv, xb[c * 576 + q0 + qq], acc[qq]);  // uniform -> s_load
        }
        ipL[p] = 1.0f / fmaxf(sqrtf(sd), 1e-12f);
        #pragma unroll
        for (int qq = 0; qq < 9; ++qq) sbuf[qq * 580 + p] = acc[qq];
    }
    __syncthreads();

    // ---- phase 2: wave wv sorts column q = q0+wv, 9-reg merge-tree (no padding) ----
    const int wv = t >> 6, lane = t & 63;
    const float ipq = ipL[q0 + wv] * 0.015625f;   // /64 ; >0, order-preserving -> deferred
    float v[9];
    {
        const float* sb2 = &sbuf[wv * 580];
        #pragma unroll
        for (int r = 0; r < 9; ++r)
            v[r] = sb2[r * 64 + lane] * ipL[r * 64 + lane];   // stride-1: conflict-free
    }

    // level 0: per-reg 64-sorts; dirs: desc {0,3,5,6}, asc {1,2,4,7,8}
    #define SSTAGE(KK, J) { \
        const bool kma = (((lane & (J)) != 0) == ((lane & (KK)) == 0)); \
        cex<J>(v[0], !kma); cex<J>(v[1],  kma); cex<J>(v[2],  kma); cex<J>(v[3], !kma); \
        cex<J>(v[4],  kma); cex<J>(v[5], !kma); cex<J>(v[6], !kma); cex<J>(v[7],  kma); \
        cex<J>(v[8],  kma); }
    SSTAGE(2, 1)
    SSTAGE(4, 2)   SSTAGE(4, 1)
    SSTAGE(8, 4)   SSTAGE(8, 2)   SSTAGE(8, 1)
    SSTAGE(16, 8)  SSTAGE(16, 4)  SSTAGE(16, 2)  SSTAGE(16, 1)
    SSTAGE(32, 16) SSTAGE(32, 8)  SSTAGE(32, 4)  SSTAGE(32, 2)  SSTAGE(32, 1)
    SSTAGE(64, 32) SSTAGE(64, 16) SSTAGE(64, 8)  SSTAGE(64, 4)  SSTAGE(64, 2) SSTAGE(64, 1)
    #undef SSTAGE

    // level 1: (0,1)->desc128, (2,3)->asc128, (4,5)->asc128, (6,7)->desc128
    cer<1>(v[0], v[1]); cer<0>(v[2], v[3]); cer<0>(v[4], v[5]); cer<1>(v[6], v[7]);
    merge64<1>(v[0], lane); merge64<1>(v[1], lane);
    merge64<0>(v[2], lane); merge64<0>(v[3], lane);
    merge64<0>(v[4], lane); merge64<0>(v[5], lane);
    merge64<1>(v[6], lane); merge64<1>(v[7], lane);

    // level 2: (0-3)->desc256, (4-7)->asc256
    cer<1>(v[0], v[2]); cer<1>(v[1], v[3]);
    cer<1>(v[0], v[1]); cer<1>(v[2], v[3]);
    merge64<1>(v[0], lane); merge64<1>(v[1], lane); merge64<1>(v[2], lane); merge64<1>(v[3], lane);
    cer<0>(v[4], v[6]); cer<0>(v[5], v[7]);
    cer<0>(v[4], v[5]); cer<0>(v[6], v[7]);
    merge64<0>(v[4], lane); merge64<0>(v[5], lane); merge64<0>(v[6], lane); merge64<0>(v[7], lane);

    // level 3: (0-7)->desc512
    cer<1>(v[0], v[4]); cer<1>(v[1], v[5]); cer<1>(v[2], v[6]); cer<1>(v[3], v[7]);
    cer<1>(v[0], v[2]); cer<1>(v[1], v[3]); cer<1>(v[4], v[6]); cer<1>(v[5], v[7]);
    cer<1>(v[0], v[1]); cer<1>(v[2], v[3]); cer<1>(v[4], v[5]); cer<1>(v[6], v[7]);
    #pragma unroll
    for (int r = 0; r < 8; ++r) merge64<1>(v[r], lane);

    // level 4: desc512 + asc64(reg8) -> desc576 (virtual 1024 merge, -inf pads folded)
    cer<1>(v[7], v[8]);
    cer<1>(v[0], v[4]); cer<1>(v[1], v[5]); cer<1>(v[2], v[6]); cer<1>(v[3], v[7]);
    cer<1>(v[0], v[2]); cer<1>(v[1], v[3]); cer<1>(v[4], v[6]); cer<1>(v[5], v[7]);
    cer<1>(v[0], v[1]); cer<1>(v[2], v[3]); cer<1>(v[4], v[5]); cer<1>(v[6], v[7]);
    #pragma unroll
    for (int r = 0; r < 8; ++r) merge64<1>(v[r], lane);
    merge64<1>(v[8], lane);

    // ---- extract ranks = round(linspace(1,575,115)) == 1 + 5i + (2i)/57 + ((2i%57)>=29)
    #pragma unroll
    for (int r = 0; r < 9; ++r) {
        const int pos = r * 64 + lane;
        const int rr0 = (int)((float)pos * 0.1993f);
        #pragma unroll
        for (int dd = -1; dd <= 2; ++dd) {
            const int cand = rr0 + dd;
            if (cand >= 0 && cand < 115) {
                const int ti = 2 * cand;
                const int rk = 1 + 5 * cand + ti / 57 + ((ti % 57) >= 29 ? 1 : 0);
                if (rk == pos) rankbuf[cand * 12 + wv] = v[r] * ipq;
            }
        }
    }
    __syncthreads();
    for (int i = t; i < 115 * 9; i += 576) {
        const int rr = i / 9, qq = i - rr * 9;
        out[(size_t)b * 66240 + rr * 576 + q0 + qq] = rankbuf[rr * 12 + qq];
    }
}

extern "C" void kernel_launch(void* const* d_in, const int* in_sizes, int n_in,
                              void* d_out, int out_size, void* d_ws, size_t ws_size,
                              hipStream_t stream) {
    const float* x = (const float*)d_in[0];   // [8,64,64,64] fp32
    float* out = (float*)d_out;               // [8,115,24,24] fp32
    float* xp = (float*)d_ws;                 // [8,64,576] = 294912 floats (~1.2 MB)

    k1<<<dim3(512), dim3(512), 0, stream>>>(x, xp);
    k3<<<dim3(512), dim3(576), 0, stream>>>(xp, out);
}

// Round 3
// 114.059 us; speedup vs baseline: 1.0755x; 1.0755x over previous
//
#include <hip/hip_runtime.h>
#include <math.h>
#include <float.h>

// b=8, c=64, H=W=64, KS=8 -> P = 57*57 = 3249.
// Stage 1 per (b,c): G[m,n] = <patch_m, patch_n> over P; corr = G/(sqrt(diag)sqrt(diag)P);
//   sort 64 m per column n desc; ranks {1,9,16,24,32,40,48,55,63} -> xp[b,c,576].
// Stage 2 per b: corr2[p,q] = sum_c Xn[c,p]Xn[c,q]/64; sort 576 p per q desc; 115 ranks.
//
// R8: k3 9-reg reg-major 576 merge-tree (zero padding).
// R9 lesson: all-VALU cross-lane was neutral on k3 and REGRESSED k1 (DPP hazard
//     nops + 4-op permlane sequences on an issue-bound VALU; LDS pipe had slack).
// R10: k1 reverted to R9-minus-one (R1 winner: shfl_xor sort, wscan+shfl_up(57)).
//      k3 restructured to 2 columns per wave (18 per block, grid=256, 1 block/CU):
//      shared stage masks, batched exchange/select over 18 chains, LB(576,2).

#define IMGS 65

// ---- DPP helpers (compile-time ctrl via templates; LDS-pipe-free cross-lane) ----
template<int CTRL, int RM>
__device__ __forceinline__ float dpp_add(float x) {
    int o = __builtin_amdgcn_update_dpp(0, __float_as_int(x), CTRL, RM, 0xf, true);
    return x + __int_as_float(o);
}
// inclusive wave64 prefix sum: row_shr 1/2/4/8, then bcast15 (rows 1,3), bcast31 (rows 2,3)
__device__ __forceinline__ float wscan_add(float x) {
    x = dpp_add<0x111, 0xf>(x);
    x = dpp_add<0x112, 0xf>(x);
    x = dpp_add<0x114, 0xf>(x);
    x = dpp_add<0x118, 0xf>(x);
    x = dpp_add<0x142, 0xa>(x);
    x = dpp_add<0x143, 0xc>(x);
    return x;
}
template<int CTRL>
__device__ __forceinline__ float dpp_perm(float x) {
    int o = __builtin_amdgcn_update_dpp(__float_as_int(x), __float_as_int(x), CTRL, 0xf, 0xf, false);
    return __int_as_float(o);
}
// xor-1 / xor-2 within quads
#define QP_XOR1 0xB1   // [1,0,3,2]
#define QP_XOR2 0x4E   // [2,3,0,1]

// ---- xor-J lane exchange: DPP for 1/2 (VALU), ds_swizzle for 4/8/16 (LDS pipe),
// ---- ds_bpermute for 32. Mixed pipes = dual-issue headroom (R9 lesson).
template<int J>
__device__ __forceinline__ float shx(float x) {
    if constexpr (J == 1)       return dpp_perm<QP_XOR1>(x);
    else if constexpr (J == 2)  return dpp_perm<QP_XOR2>(x);
    else if constexpr (J <= 16)
        return __int_as_float(__builtin_amdgcn_ds_swizzle(__float_as_int(x), (J << 10) | 0x1F));
    else
        return __shfl_xor(x, 32, 64);
}

template<int J>
__device__ __forceinline__ void cex(float& v, const bool keep_max) {
    const float o = shx<J>(v);
    v = keep_max ? fmaxf(v, o) : fminf(v, o);
}

// in-lane compare-exchange between two regs; DESC: a (lower position) keeps max
template<int DESC>
__device__ __forceinline__ void cer(float& a, float& b) {
    const float mx = fmaxf(a, b), mn = fminf(a, b);
    if constexpr (DESC) { a = mx; b = mn; } else { a = mn; b = mx; }
}

__host__ __device__ constexpr int offF(int dj) { return dj * (17 - dj) / 2; }       // 36 total
__host__ __device__ constexpr int offB(int dj) { return (dj - 1) * (16 - dj) / 2; } // 28 total

// ---------------- k1: fused stage-1, pair-symmetric, canonical-G (R1 winner) ----------------
// grid = 512 (bc), block = 512 (8 waves; wave wv handles row-shift d = wv)
__global__ __launch_bounds__(512) void k1(const float* __restrict__ x,
                                          float* __restrict__ xp) {
    __shared__ float img[64 * IMGS];   // 16.6 KB
    __shared__ float G[64 * IMGS];     // canonical: G[m*65+n], m<=n

    const int t = threadIdx.x;
    const int bc = blockIdx.x;
    const float* src = x + (size_t)bc * 4096;

    #pragma unroll
    for (int k = 0; k < 2; ++k) {
        int i4 = t + k * 512;
        float4 v = ((const float4*)src)[i4];
        int fl = i4 * 4, row = fl >> 6, col = fl & 63;
        float* dd = &img[row * IMGS + col];
        dd[0] = v.x; dd[1] = v.y; dd[2] = v.z; dd[3] = v.w;
    }
    __syncthreads();

    const int wv = t >> 6, lane = t & 63;
    const int d = wv;                            // 0..7
    const int a = lane;
    const bool av = (a + d <= 63);
    const int a1 = min(a + d, 63);
    const float* r0 = &img[a * IMGS];
    const float* r1 = &img[a1 * IMGS];

    // ---- FMA phase: wf[k]=sum r0[u]*r1[u+k], wb[k]=sum r1[u]*r0[u+k]  (u=0..56) ----
    float wf[8] = {0,0,0,0,0,0,0,0}, wb[8] = {0,0,0,0,0,0,0,0};
    float sf[8], sb[8], hf[7], hb[7];
    #pragma unroll
    for (int k = 0; k < 7; ++k) { sf[k] = r1[k]; sb[k] = r0[k]; hf[k] = sf[k]; hb[k] = sb[k]; }
    #pragma unroll
    for (int c = 0; c < 7; ++c) {
        #pragma unroll
        for (int j = 0; j < 8; ++j) {
            const int u = c * 8 + j;
            sf[(j + 7) & 7] = r1[u + 7];
            sb[(j + 7) & 7] = r0[u + 7];
            const float f0 = sb[j & 7];          // r0[u]
            const float g0 = sf[j & 7];          // r1[u]
            #pragma unroll
            for (int k = 0; k < 8; ++k) wf[k] = fmaf(f0, sf[(j + k) & 7], wf[k]);
            #pragma unroll
            for (int k = 1; k < 8; ++k) wb[k] = fmaf(g0, sb[(j + k) & 7], wb[k]);
        }
    }
    {   // u = 56 (j-pattern 0)
        sf[7] = r1[63]; sb[7] = r0[63];
        const float f0 = sb[0], g0 = sf[0];
        #pragma unroll
        for (int k = 0; k < 8; ++k) wf[k] = fmaf(f0, sf[k], wf[k]);
        #pragma unroll
        for (int k = 1; k < 8; ++k) wb[k] = fmaf(g0, sb[k], wb[k]);
    }
    // now sf[k] = r1[56+k], sb[k] = r0[56+k]  (tails); hf/hb = heads

    // ---- slide over st (all indices compile-time) ----
    float Wf[36], Wb[28];
    #pragma unroll
    for (int dj = 0; dj < 8; ++dj) {
        float a0 = wf[dj];
        Wf[offF(dj)] = a0;
        #pragma unroll
        for (int st = 1; st < 8 - dj; ++st) {
            a0 += sb[st] * sf[st + dj] - hb[st - 1] * hf[st - 1 + dj];
            Wf[offF(dj) + st] = a0;
        }
    }
    #pragma unroll
    for (int dj = 1; dj < 8; ++dj) {
        float a0 = wb[dj];
        Wb[offB(dj)] = a0;
        #pragma unroll
        for (int st = 1; st < 8 - dj; ++st) {
            a0 += sf[st] * sb[st + dj] - hf[st - 1] * hb[st - 1 + dj];
            Wb[offB(dj) + st] = a0;
        }
    }

    // ---- mask invalid rows, DPP prefix-scan over lanes (rows a) ----
    const float msk = av ? 1.0f : 0.0f;
    #pragma unroll
    for (int i = 0; i < 36; ++i) Wf[i] = wscan_add(Wf[i] * msk);
    if (d > 0) {
        #pragma unroll
        for (int i = 0; i < 28; ++i) Wb[i] = wscan_add(Wb[i] * msk);
    }

    // ---- extract: S(ki) on lane ki+56 = P[lane] - P[lane-57]; write canonical G ----
    const bool wr = (lane >= 56) && (lane <= 63 - d);
    const int ki = lane - 56;
    #pragma unroll
    for (int dj = 0; dj < 8; ++dj) {
        #pragma unroll
        for (int st = 0; st < 8 - dj; ++st) {
            {
                float P = Wf[offF(dj) + st];
                float sl = __shfl_up(P, 57, 64);
                float S = P - (lane >= 57 ? sl : 0.0f);
                if (wr) G[(ki * 8 + st) * IMGS + ((ki + d) * 8 + st + dj)] = S;
            }
            if (d > 0 && dj > 0) {
                float P = Wb[offB(dj) + st];
                float sl = __shfl_up(P, 57, 64);
                float S = P - (lane >= 57 ? sl : 0.0f);
                if (wr) G[(ki * 8 + st + dj) * IMGS + ((ki + d) * 8 + st)] = S;
            }
        }
    }
    __syncthreads();

    // ---- normalize + batched sort64 (wave wv: columns wv*8..wv*8+7) ----
    const int m = lane;
    const float invm = 1.0f / fmaxf(sqrtf(G[m * 66]), 1e-12f);
    const float sc = 1.0f / 3249.0f;
    const int c0 = wv * 8;
    float v[8];
    #pragma unroll
    for (int cc = 0; cc < 8; ++cc) {
        const int col = c0 + cc;
        const int addr = (m <= col) ? m * IMGS + col : col * IMGS + m;   // symmetric read
        const float invc = __shfl(invm, col, 64);
        v[cc] = G[addr] * invm * invc * sc;
    }
    #pragma unroll
    for (int kk = 2; kk <= 64; kk <<= 1) {
        #pragma unroll
        for (int j = kk >> 1; j > 0; j >>= 1) {
            const bool upper = (lane & j) != 0;
            const bool dir0  = (lane & kk) == 0;
            const bool keep_max = dir0 ^ upper;
            float o[8];
            #pragma unroll
            for (int cc = 0; cc < 8; ++cc) {
                if (j == 1)      o[cc] = dpp_perm<QP_XOR1>(v[cc]);
                else if (j == 2) o[cc] = dpp_perm<QP_XOR2>(v[cc]);
                else             o[cc] = __shfl_xor(v[cc], j, 64);
            }
            #pragma unroll
            for (int cc = 0; cc < 8; ++cc)
                v[cc] = keep_max ? fmaxf(v[cc], o[cc]) : fminf(v[cc], o[cc]);
        }
    }
    // ranks2 = {1,9,16,24,32,40,48,55,63}
    int ridx = -1;
    if      (lane ==  1) ridx = 0; else if (lane ==  9) ridx = 1; else if (lane == 16) ridx = 2;
    else if (lane == 24) ridx = 3; else if (lane == 32) ridx = 4; else if (lane == 40) ridx = 5;
    else if (lane == 48) ridx = 6; else if (lane == 55) ridx = 7; else if (lane == 63) ridx = 8;
    if (ridx >= 0) {
        float* dst = xp + (size_t)bc * 576 + ridx * 64 + c0;
        *(float4*)&dst[0] = make_float4(v[0], v[1], v[2], v[3]);
        *(float4*)&dst[4] = make_float4(v[4], v[5], v[6], v[7]);
    }
}

// ---------------- k3: fused stage-2, 2 columns per wave ----------------
// grid = 8*32 (b x q-group of 18), block = 576 (9 waves; wave wv sorts cols q0+wv, q0+9+wv)
__global__ __launch_bounds__(576, 2) void k3(const float* __restrict__ xp,
                                             float* __restrict__ out) {
    __shared__ __align__(16) float sbuf[18 * 580];  // raw corr columns, stride 580 (~42 KB)
    __shared__ __align__(16) float ipL[576];        // per-p inverse channel norms
    __shared__ float rankbuf[115 * 19];
    const int t = threadIdx.x;
    const int b = blockIdx.x >> 5, qg = blockIdx.x & 31;
    const int q0 = qg * 18;
    const float* __restrict__ xb = xp + (size_t)b * 36864;

    // ---- phase 1: thread p computes raw corr2 col entries for 18 q's + own norm ----
    {
        const int p = t;
        float acc[18];
        #pragma unroll
        for (int qq = 0; qq < 18; ++qq) acc[qq] = 0.f;
        float sd = 0.f;
        #pragma unroll 4
        for (int c = 0; c < 64; ++c) {
            const float xv = xb[c * 576 + p];                  // coalesced vector load
            sd = fmaf(xv, xv, sd);
            #pragma unroll
            for (int qq = 0; qq < 18; ++qq)
                acc[qq] = fmaf(xv, xb[c * 576 + q0 + qq], acc[qq]);  // uniform -> s_load
        }
        ipL[p] = 1.0f / fmaxf(sqrtf(sd), 1e-12f);
        #pragma unroll
        for (int qq = 0; qq < 18; ++qq) sbuf[qq * 580 + p] = acc[qq];
    }
    __syncthreads();

    // ---- phase 2: wave wv sorts columns A=q0+wv (V[0..8]) and B=q0+9+wv (V[9..17]) ----
    const int wv = t >> 6, lane = t & 63;
    const float ipqA = ipL[q0 + wv] * 0.015625f;       // /64 ; >0, deferred to extraction
    const float ipqB = ipL[q0 + 9 + wv] * 0.015625f;
    float V[18];
    {
        const float* sA = &sbuf[wv * 580];
        const float* sB = &sbuf[(9 + wv) * 580];
        #pragma unroll
        for (int r = 0; r < 9; ++r) {
            const float ip = ipL[r * 64 + lane];
            V[r]     = sA[r * 64 + lane] * ip;         // stride-1: conflict-free
            V[9 + r] = sB[r * 64 + lane] * ip;
        }
    }

    // ---- level 0: per-reg 64-sorts; per-col dirs: desc {0,3,5,6}, asc {1,2,4,7,8} ----
    // shared mask per stage; batched exchange then batched select (18-way ILP)
    #define ST0(KK, J) { \
        const bool kma = (((lane & (J)) != 0) == ((lane & (KK)) == 0)); \
        float o[18]; \
        _Pragma("unroll") for (int r = 0; r < 18; ++r) o[r] = shx<J>(V[r]); \
        _Pragma("unroll") for (int r = 0; r < 18; ++r) { \
            const int rb = r % 9; \
            const bool dsc = (rb == 0 || rb == 3 || rb == 5 || rb == 6); \
            const bool km = dsc ? !kma : kma; \
            V[r] = km ? fmaxf(V[r], o[r]) : fminf(V[r], o[r]); } }
    ST0(2, 1)
    ST0(4, 2)   ST0(4, 1)
    ST0(8, 4)   ST0(8, 2)   ST0(8, 1)
    ST0(16, 8)  ST0(16, 4)  ST0(16, 2)  ST0(16, 1)
    ST0(32, 16) ST0(32, 8)  ST0(32, 4)  ST0(32, 2)  ST0(32, 1)
    ST0(64, 32) ST0(64, 16) ST0(64, 8)  ST0(64, 4)  ST0(64, 2)  ST0(64, 1)
    #undef ST0

    // merge stage over regs 0..7 of both cols; DESCEXPR in terms of q = reg index 0..7
    #define STM16(J, DESCEXPR) { \
        const bool kma = ((lane & (J)) != 0); \
        float o[16]; \
        _Pragma("unroll") for (int rr = 0; rr < 16; ++rr) { \
            const int r = (rr < 8) ? rr : (rr + 1); o[rr] = shx<J>(V[r]); } \
        _Pragma("unroll") for (int rr = 0; rr < 16; ++rr) { \
            const int r = (rr < 8) ? rr : (rr + 1); const int q = rr & 7; \
            const bool dsc = (DESCEXPR); \
            const bool km = dsc ? !kma : kma; \
            V[r] = km ? fmaxf(V[r], o[rr]) : fminf(V[r], o[rr]); } }
    #define MERGE16(DESCEXPR) \
        STM16(32, DESCEXPR) STM16(16, DESCEXPR) STM16(8, DESCEXPR) \
        STM16(4, DESCEXPR)  STM16(2, DESCEXPR)  STM16(1, DESCEXPR)

    // merge stage over ALL 18 regs, descending
    #define STM18(J) { \
        const bool kma = ((lane & (J)) != 0); \
        float o[18]; \
        _Pragma("unroll") for (int r = 0; r < 18; ++r) o[r] = shx<J>(V[r]); \
        _Pragma("unroll") for (int r = 0; r < 18; ++r) \
            V[r] = (!kma) ? fmaxf(V[r], o[r]) : fminf(V[r], o[r]); }

    // ---- level 1: (0,1)->desc128, (2,3)->asc128, (4,5)->asc128, (6,7)->desc128 ----
    cer<1>(V[0], V[1]);  cer<0>(V[2], V[3]);  cer<0>(V[4], V[5]);  cer<1>(V[6], V[7]);
    cer<1>(V[9], V[10]); cer<0>(V[11], V[12]); cer<0>(V[13], V[14]); cer<1>(V[15], V[16]);
    MERGE16((q == 0 || q == 1 || q == 6 || q == 7))

    // ---- level 2: (0-3)->desc256, (4-7)->asc256 ----
    cer<1>(V[0], V[2]);  cer<1>(V[1], V[3]);  cer<1>(V[0], V[1]);  cer<1>(V[2], V[3]);
    cer<0>(V[4], V[6]);  cer<0>(V[5], V[7]);  cer<0>(V[4], V[5]);  cer<0>(V[6], V[7]);
    cer<1>(V[9], V[11]); cer<1>(V[10], V[12]); cer<1>(V[9], V[10]); cer<1>(V[11], V[12]);
    cer<0>(V[13], V[15]); cer<0>(V[14], V[16]); cer<0>(V[13], V[14]); cer<0>(V[15], V[16]);
    MERGE16((q < 4))

    // ---- level 3: (0-7)->desc512 ----
    cer<1>(V[0], V[4]);  cer<1>(V[1], V[5]);  cer<1>(V[2], V[6]);  cer<1>(V[3], V[7]);
    cer<1>(V[9], V[13]); cer<1>(V[10], V[14]); cer<1>(V[11], V[15]); cer<1>(V[12], V[16]);
    cer<1>(V[0], V[2]);  cer<1>(V[1], V[3]);  cer<1>(V[4], V[6]);  cer<1>(V[5], V[7]);
    cer<1>(V[9], V[11]); cer<1>(V[10], V[12]); cer<1>(V[13], V[15]); cer<1>(V[14], V[16]);
    cer<1>(V[0], V[1]);  cer<1>(V[2], V[3]);  cer<1>(V[4], V[5]);  cer<1>(V[6], V[7]);
    cer<1>(V[9], V[10]); cer<1>(V[11], V[12]); cer<1>(V[13], V[14]); cer<1>(V[15], V[16]);
    MERGE16(true)

    // ---- level 4: desc512 + asc64(reg8) -> desc576 (virtual 1024 merge, pads folded) ----
    cer<1>(V[7], V[8]);  cer<1>(V[16], V[17]);
    cer<1>(V[0], V[4]);  cer<1>(V[1], V[5]);  cer<1>(V[2], V[6]);  cer<1>(V[3], V[7]);
    cer<1>(V[9], V[13]); cer<1>(V[10], V[14]); cer<1>(V[11], V[15]); cer<1>(V[12], V[16]);
    cer<1>(V[0], V[2]);  cer<1>(V[1], V[3]);  cer<1>(V[4], V[6]);  cer<1>(V[5], V[7]);
    cer<1>(V[9], V[11]); cer<1>(V[10], V[12]); cer<1>(V[13], V[15]); cer<1>(V[14], V[16]);
    cer<1>(V[0], V[1]);  cer<1>(V[2], V[3]);  cer<1>(V[4], V[5]);  cer<1>(V[6], V[7]);
    cer<1>(V[9], V[10]); cer<1>(V[11], V[12]); cer<1>(V[13], V[14]); cer<1>(V[15], V[16]);
    STM18(32) STM18(16) STM18(8) STM18(4) STM18(2) STM18(1)

    #undef STM18
    #undef MERGE16
    #undef STM16

    // ---- extract ranks = round(linspace(1,575,115)) == 1 + 5i + (2i)/57 + ((2i%57)>=29)
    // sorted descending position of reg r = r*64 + lane (same for both columns)
    #pragma unroll
    for (int r = 0; r < 9; ++r) {
        const int pos = r * 64 + lane;
        const int rr0 = (int)((float)pos * 0.1993f);
        #pragma unroll
        for (int dd = -1; dd <= 2; ++dd) {
            const int cand = rr0 + dd;
            if (cand >= 0 && cand < 115) {
                const int ti = 2 * cand;
                const int rk = 1 + 5 * cand + ti / 57 + ((ti % 57) >= 29 ? 1 : 0);
                if (rk == pos) {
                    rankbuf[cand * 19 + wv]     = V[r] * ipqA;
                    rankbuf[cand * 19 + 9 + wv] = V[9 + r] * ipqB;
                }
            }
        }
    }
    __syncthreads();
    for (int i = t; i < 115 * 18; i += 576) {
        const int rr = i / 18, qq = i - rr * 18;
        out[(size_t)b * 66240 + rr * 576 + q0 + qq] = rankbuf[rr * 19 + qq];
    }
}

extern "C" void kernel_launch(void* const* d_in, const int* in_sizes, int n_in,
                              void* d_out, int out_size, void* d_ws, size_t ws_size,
                              hipStream_t stream) {
    const float* x = (const float*)d_in[0];   // [8,64,64,64] fp32
    float* out = (float*)d_out;               // [8,115,24,24] fp32
    float* xp = (float*)d_ws;                 // [8,64,576] = 294912 floats (~1.2 MB)

    k1<<<dim3(512), dim3(512), 0, stream>>>(x, xp);
    k3<<<dim3(256), dim3(576), 0, stream>>>(xp, out);
}